// Round 2
// baseline (8979.543 us; speedup 1.0000x reference)
//
#include <hip/hip_runtime.h>
#include <math.h>

#define NN 4096
#define MAX_SWEEPS 12

// psi(k) = alpha*k in GF(2^6), primitive poly x^6 + x + 1.
// Orbit of 1 under psi = all 63 nonzero masks, period 63.
__host__ __device__ constexpr int psi_step(int k) {
  return ((k << 1) & 63) ^ ((k & 32) ? 3 : 0);
}

struct CycTab {
  int c[63];
  constexpr CycTab() : c{} {
    int x = 1;
    for (int j = 0; j < 63; ++j) { c[j] = x; x = psi_step(x); }
  }
};
static constexpr CycTab CYC{};

// One wave (64 lanes) per 64x64 matrix. Register-resident two-sided Jacobi:
//   a[k] = A[lane][lane ^ phi(k)],  v[k] = V[lane][lane ^ phi(k)],
// phi = psi^round (linear over GF(2)^6; identity at every sweep boundary).
// Invariants: diag at a[0]; pair off-diag at a[1]; column-rotation reg pairs
// are (2t,2t+1); row-rotation partner of a[k] is shfl_xor(a[k^1], m).
__global__ __launch_bounds__(64) void logeig_jacobi_reg(
    const float* __restrict__ X, float* __restrict__ out) {
  __shared__ float lds[NN];
  const int lane = threadIdx.x;
  const size_t base = (size_t)blockIdx.x * NN;

  // ---- stage X -> LDS (coalesced float4), then regs in XOR layout ----
  {
    const float4* Xg = (const float4*)(X + base);
    float4* L4 = (float4*)lds;
#pragma unroll
    for (int ch = 0; ch < 16; ++ch) L4[lane + 64 * ch] = Xg[lane + 64 * ch];
  }
  __syncthreads();

  float a[64], v[64];
#pragma unroll
  for (int r = 0; r < 64; ++r) a[r] = lds[lane * 64 + (lane ^ r)];  // bank = (lane^r)&31: conflict-free
#pragma unroll
  for (int r = 1; r < 64; ++r) v[r] = 0.0f;
  v[0] = 1.0f;

  // phi state (wave-uniform -> SGPRs): m = phi(1); Bj = phi(2^{j+1}).
  int m = 1, B0 = 2, B1 = 4, B2 = 8, B3 = 16, B4 = 32;

#pragma unroll 1
  for (int sw = 0; sw < MAX_SWEEPS; ++sw) {
#pragma unroll 1
    for (int rr = 0; rr < 63; ++rr) {
      // ---- angles: every lane computes rotation of its pair {lane, lane^m} ----
      // apq SYMMETRIZED across the pair: both lanes see bit-identical
      // (app,aqq,apq) -> bit-identical (c,s). Without this, lanes p and q
      // derive slightly different rotations from A[p][q] vs A[q][p] (ulp
      // asymmetry amplified by small diagonal gaps), the update stops being
      // an orthogonal similarity, and V drifts ~1e-1 over 600 rounds.
      const float mydg = a[0];
      const float otdg = __shfl_xor(mydg, m);
      const float apq = 0.5f * (a[1] + __shfl_xor(a[1], m));
      const bool isq = (lane ^ m) < lane;  // true iff I'm the higher (q) index
      const float app = isq ? otdg : mydg;
      const float aqq = isq ? mydg : otdg;
      float c = 1.0f, s = 0.0f;
      if (fabsf(apq) > 1e-37f) {           // converged pair -> identity rotation
        const float tau = (aqq - app) / (2.0f * apq);
        float t = 1.0f / (fabsf(tau) + sqrtf(1.0f + tau * tau));
        t = (tau >= 0.0f) ? t : -t;
        c = 1.0f / sqrtf(1.0f + t * t);
        s = t * c;
      }
      const float st = isq ? -s : s;       // sign-folded s: gathers arrive correctly signed

      // ---- column rotations on A and V (all 32 pairs, Gray-ordered slots) ----
      // Reg pair (K,K+1) holds columns {lane^u, lane^u^m}; its angle lives in lane (lane^u),
      // where u = phi(K) is built incrementally: Gray step t->t+1 XORs basis image B_ctz(t+1).
      {
        const int Bv[5] = {B0, B1, B2, B3, B4};
        int u = 0;
#pragma unroll
        for (int t = 0; t < 32; ++t) {
          const int K = (t ^ (t >> 1)) << 1;
          float cg, sg;
          if (t == 0) { cg = c; sg = st; }          // u==0: own pair
          else { cg = __shfl_xor(c, u); sg = __shfl_xor(st, u); }
          const float ax = a[K], ay = a[K + 1];
          a[K]     = cg * ax - sg * ay;
          a[K + 1] = sg * ax + cg * ay;
          const float vx = v[K], vy = v[K + 1];
          v[K]     = cg * vx - sg * vy;
          v[K + 1] = sg * vx + cg * vy;
          if (t < 31) u ^= Bv[__builtin_ctz(t + 1)];
        }
      }

      // ---- row rotations: rows lane and lane^m mix, lane-own angle ----
      // Partner holds my column phi(k) at its reg k^1. Reads (shfl) before writes per pair.
#pragma unroll
      for (int K = 0; K < 64; K += 2) {
        const float p0 = __shfl_xor(a[K + 1], m);
        const float p1 = __shfl_xor(a[K], m);
        a[K]     = c * a[K]     - st * p0;
        a[K + 1] = c * a[K + 1] - st * p1;
      }

      // ---- register relabel a[k] <- a[psi(k)] (single fixed 63-cycle; 0 fixed) ----
      {
        float ta = a[CYC.c[0]], tv = v[CYC.c[0]];
#pragma unroll
        for (int j = 0; j < 62; ++j) {
          a[CYC.c[j]] = a[CYC.c[j + 1]];
          v[CYC.c[j]] = v[CYC.c[j + 1]];
        }
        a[CYC.c[62]] = ta;
        v[CYC.c[62]] = tv;
      }

      // ---- advance phi: new m = phi(psi(1)) = B0; new B4 = phi(psi(32)) = phi(3) = m^B0 ----
      const int nB4 = m ^ B0;
      m = B0; B0 = B1; B1 = B2; B2 = B3; B3 = B4; B4 = nB4;
    }

    // ---- convergence check (phi = identity here): exit at fp32 noise level ----
    float offs = 0.0f, dias = a[0] * a[0];
#pragma unroll
    for (int k = 1; k < 64; ++k) offs = fmaf(a[k], a[k], offs);
#pragma unroll
    for (int o = 1; o < 64; o <<= 1) {   // butterfly all-reduce: all lanes identical -> uniform branch
      offs += __shfl_xor(offs, o);
      dias += __shfl_xor(dias, o);
    }
    if (offs <= 1e-13f * dias) break;
  }

  // ---- epilogue: Y = V diag(log lambda) V^T ----
  // lambda_c = diag element of lane c; ll broadcast via shfl_xor.
  const float ll = logf(fmaxf(a[0], 1e-30f));  // clamp: never NaN/inf
  __syncthreads();
  // W[l][c] = V[l][c]*log(lambda_c), c = lane^r -> plain layout lds[l*64 + c];
  // write bank = (r^lane)&31: conflict-free.
#pragma unroll
  for (int r = 0; r < 64; ++r)
    lds[lane * 64 + (r ^ lane)] = v[r] * __shfl_xor(ll, r);
  __syncthreads();

  // Y[i][lane] = sum_k W[i][k] * V[lane][k] = sum_r W[i][lane^r] * v[r]
  // read bank = (lane^r)&31: conflict-free; stores coalesced 256B.
  float* Og = out + base;
#pragma unroll 1
  for (int i = 0; i < 64; ++i) {
    const float* Wrow = lds + i * 64;
    float acc0 = 0.0f, acc1 = 0.0f;
#pragma unroll
    for (int r = 0; r < 64; r += 2) {
      acc0 = fmaf(Wrow[lane ^ r], v[r], acc0);
      acc1 = fmaf(Wrow[lane ^ (r + 1)], v[r + 1], acc1);
    }
    Og[i * 64 + lane] = acc0 + acc1;
  }
}

extern "C" void kernel_launch(void* const* d_in, const int* in_sizes, int n_in,
                              void* d_out, int out_size, void* d_ws, size_t ws_size,
                              hipStream_t stream) {
  const float* X = (const float*)d_in[0];
  float* out = (float*)d_out;
  const int nmat = in_sizes[0] / NN;  // 8192
  logeig_jacobi_reg<<<nmat, 64, 0, stream>>>(X, out);
}

// Round 3
// 6153.432 us; speedup vs baseline: 1.4593x; 1.4593x over previous
//
#include <hip/hip_runtime.h>
#include <math.h>

#define NN 4096
#define MAX_SWEEPS 12

typedef float f2 __attribute__((ext_vector_type(2)));

// psi(k) = alpha*k in GF(2^6), primitive poly x^6 + x + 1. Orbit of 1 = all 63 masks.
constexpr int psi_step(int k) { return ((k << 1) & 63) ^ ((k & 32) ? 3 : 0); }
struct CycTab {
  int c[63];
  constexpr CycTab() : c{} {
    int x = 1;
    for (int j = 0; j < 63; ++j) { c[j] = x; x = psi_step(x); }
  }
};
static constexpr CycTab CYC{};

__device__ __forceinline__ float bperm(int addr, float x) {
  return __int_as_float(__builtin_amdgcn_ds_bpermute(addr, __float_as_int(x)));
}

// cs={c,s}, xy={x,y} -> {c*x - s*y, s*x + c*y}   (2 packed-f32 ops)
__device__ __forceinline__ f2 colrot(f2 cs, f2 xy) {
  f2 t, d;
  // t = { -s*y, c*y }
  asm("v_pk_mul_f32 %0, %1, %2 op_sel:[1,1] op_sel_hi:[0,1] neg_lo:[1,0]"
      : "=v"(t) : "v"(cs), "v"(xy));
  // d = { c*x + t.lo, s*x + t.hi }
  asm("v_pk_fma_f32 %0, %1, %2, %3 op_sel:[0,0,0] op_sel_hi:[1,0,1]"
      : "=v"(d) : "v"(cs), "v"(xy), "v"(t));
  return d;
}
// cs={c,st}, a, p -> {c*a.x - st*p.y, c*a.y - st*p.x}   (row update; p = shfl'd slot)
__device__ __forceinline__ f2 rowrot(f2 cs, f2 a, f2 p) {
  f2 t, d;
  // t = { -st*p.hi, -st*p.lo }
  asm("v_pk_mul_f32 %0, %1, %2 op_sel:[1,1] op_sel_hi:[1,0] neg_lo:[1,0] neg_hi:[1,0]"
      : "=v"(t) : "v"(cs), "v"(p));
  // d = { c*a.lo + t.lo, c*a.hi + t.hi }
  asm("v_pk_fma_f32 %0, %1, %2, %3 op_sel:[0,0,0] op_sel_hi:[0,1,1]"
      : "=v"(d) : "v"(cs), "v"(a), "v"(t));
  return d;
}

// One wave per 64x64 SPD matrix. a2/v2 pack a[k]=A[lane][lane^phi(k)] as f2 pairs
// (k = 2t,2t+1). Same rotation schedule as the verified scalar kernel: column pairs
// are f2 slots, angle gathered from lane^u via Gray-walked bpermute address; row
// partner is swap(shfl_xor(slot, m)); per-round relabel a[k]<-a[psi(k)].
__global__ __launch_bounds__(64, 2) void logeig_jacobi_pk(
    const float* __restrict__ X, float* __restrict__ out) {
  __shared__ float lds[1024];  // 4 KB: 16-row chunks for prologue/epilogue
  const int lane = threadIdx.x;
  const size_t base = (size_t)blockIdx.x * NN;

  f2 a2[32], v2[32];

  // ---- prologue: stage 16 rows at a time; lane extracts its own row in XOR layout ----
  {
    const float4* Xg = (const float4*)(X + base);
    float4* L4 = (float4*)lds;
    for (int ch = 0; ch < 4; ++ch) {
#pragma unroll
      for (int i = 0; i < 4; ++i) L4[lane + 64 * i] = Xg[ch * 256 + lane + 64 * i];
      __syncthreads();
      if ((lane >> 4) == ch) {  // my row lives in this chunk
        const int lr = (lane & 15) << 6;
#pragma unroll
        for (int r = 0; r < 64; ++r) {  // 16 lanes -> 16 distinct banks: conflict-free
          const float val = lds[lr + (lane ^ r)];
          if (r & 1) a2[r >> 1].y = val; else a2[r >> 1].x = val;
        }
      }
      __syncthreads();
    }
  }
#pragma unroll
  for (int t = 1; t < 32; ++t) { v2[t].x = 0.0f; v2[t].y = 0.0f; }
  v2[0].x = 1.0f; v2[0].y = 0.0f;

  // phi state (wave-uniform -> SGPRs): m = phi(1); Bj = phi(2^{j+1}).
  int m = 1, B0 = 2, B1 = 4, B2 = 8, B3 = 16, B4 = 32;

#pragma unroll 1
  for (int sw = 0; sw < MAX_SWEEPS; ++sw) {
#pragma unroll 1
    for (int rr = 0; rr < 63; ++rr) {
      const int maddr = (lane ^ m) << 2;  // shared bpermute address for angle+row phases
      // ---- angles (apq symmetrized: both pair lanes get bit-identical c,s) ----
      const float mydg = a2[0].x;
      const float otdg = bperm(maddr, mydg);
      const float apq = 0.5f * (a2[0].y + bperm(maddr, a2[0].y));
      const bool isq = (lane ^ m) < lane;
      const float app = isq ? otdg : mydg;
      const float aqq = isq ? mydg : otdg;
      float c = 1.0f, s = 0.0f;
      if (fabsf(apq) > 1e-37f) {
        const float tau = (aqq - app) / (2.0f * apq);
        float tt = 1.0f / (fabsf(tau) + sqrtf(1.0f + tau * tau));
        tt = (tau >= 0.0f) ? tt : -tt;
        c = rsqrtf(1.0f + tt * tt);  // c,s deterministic+identical in both lanes
        s = tt * c;
      }
      const float st = isq ? -s : s;  // sign-folded s
      const f2 cst0 = {c, st};

      // ---- column rotations (A and V), Gray-ordered slots, 2 pk-ops per rotation ----
      {
        const int Bsh[5] = {B0 << 2, B1 << 2, B2 << 2, B3 << 2, B4 << 2};
        int uaddr = lane << 2;  // (lane ^ u)<<2, u Gray-walked
#pragma unroll
        for (int t = 0; t < 32; ++t) {
          const int slot = t ^ (t >> 1);
          f2 csg;
          if (t == 0) csg = cst0;
          else { csg.x = bperm(uaddr, cst0.x); csg.y = bperm(uaddr, cst0.y); }
          a2[slot] = colrot(csg, a2[slot]);
          v2[slot] = colrot(csg, v2[slot]);
          if (t < 31) uaddr ^= Bsh[__builtin_ctz(t + 1)];
        }
      }

      // ---- row rotations: partner slot value via 2 bpermutes sharing maddr ----
#pragma unroll
      for (int t = 0; t < 32; ++t) {
        f2 p;
        p.x = bperm(maddr, a2[t].x);
        p.y = bperm(maddr, a2[t].y);
        a2[t] = rowrot(cst0, a2[t], p);
      }

      // ---- relabel a[k] <- a[psi(k)] (fixed 63-cycle, component-static after unroll) ----
      {
        const int h = CYC.c[0];
        const float ta = (h & 1) ? a2[h >> 1].y : a2[h >> 1].x;
        const float tv = (h & 1) ? v2[h >> 1].y : v2[h >> 1].x;
#pragma unroll
        for (int j = 0; j < 62; ++j) {
          const int dd = CYC.c[j], ss2 = CYC.c[j + 1];
          const float sa = (ss2 & 1) ? a2[ss2 >> 1].y : a2[ss2 >> 1].x;
          const float sv = (ss2 & 1) ? v2[ss2 >> 1].y : v2[ss2 >> 1].x;
          if (dd & 1) { a2[dd >> 1].y = sa; v2[dd >> 1].y = sv; }
          else        { a2[dd >> 1].x = sa; v2[dd >> 1].x = sv; }
        }
        const int l_ = CYC.c[62];
        if (l_ & 1) { a2[l_ >> 1].y = ta; v2[l_ >> 1].y = tv; }
        else        { a2[l_ >> 1].x = ta; v2[l_ >> 1].x = tv; }
      }

      // ---- advance phi ----
      const int nB4 = m ^ B0;
      m = B0; B0 = B1; B1 = B2; B2 = B3; B3 = B4; B4 = nB4;
    }

    // ---- convergence check (phi = identity here) ----
    float offs = a2[0].y * a2[0].y, dias = a2[0].x * a2[0].x;
#pragma unroll
    for (int t = 1; t < 32; ++t) {
      offs = fmaf(a2[t].x, a2[t].x, offs);
      offs = fmaf(a2[t].y, a2[t].y, offs);
    }
#pragma unroll
    for (int o = 1; o < 64; o <<= 1) {  // butterfly: all lanes identical -> uniform branch
      offs += __shfl_xor(offs, o);
      dias += __shfl_xor(dias, o);
    }
    if (offs <= 1e-13f * dias) break;
  }

  // ---- epilogue: Y = V diag(log lam) V^T, tiled 16 rows / 4 KB ----
  const float ll = logf(fmaxf(a2[0].x, 1e-30f));  // clamp: never NaN/inf
  // a2 is dead: reuse as la[r] = log lam of column lane^r
#pragma unroll
  for (int r = 0; r < 64; ++r) {
    const float lr_ = __shfl_xor(ll, r);
    if (r & 1) a2[r >> 1].y = lr_; else a2[r >> 1].x = lr_;
  }
  __syncthreads();
  float* Og = out + base;
  for (int tt = 0; tt < 4; ++tt) {
    if ((lane >> 4) == tt) {  // write W rows of this tile (16 lanes, distinct banks)
      const int lr = (lane & 15) << 6;
#pragma unroll
      for (int t = 0; t < 32; ++t) {
        const f2 w = v2[t] * a2[t];
        lds[lr + ((2 * t) ^ lane)] = w.x;
        lds[lr + ((2 * t + 1) ^ lane)] = w.y;
      }
    }
    __syncthreads();
#pragma unroll 1
    for (int ii = 0; ii < 16; ++ii) {  // all lanes: Y[row][lane]; 2 lanes/bank = free
      const float* Wrow = lds + (ii << 6);
      float acc0 = 0.0f, acc1 = 0.0f;
#pragma unroll
      for (int t = 0; t < 32; ++t) {
        acc0 = fmaf(Wrow[lane ^ (2 * t)], v2[t].x, acc0);
        acc1 = fmaf(Wrow[lane ^ (2 * t + 1)], v2[t].y, acc1);
      }
      Og[((tt << 4) + ii) * 64 + lane] = acc0 + acc1;
    }
    __syncthreads();
  }
}

extern "C" void kernel_launch(void* const* d_in, const int* in_sizes, int n_in,
                              void* d_out, int out_size, void* d_ws, size_t ws_size,
                              hipStream_t stream) {
  const float* X = (const float*)d_in[0];
  float* out = (float*)d_out;
  const int nmat = in_sizes[0] / NN;  // 8192
  logeig_jacobi_pk<<<nmat, 64, 0, stream>>>(X, out);
}